// Round 18
// baseline (241.093 us; speedup 1.0000x reference)
//
#include <hip/hip_runtime.h>
#include <hip/hip_bf16.h>

// ---------------------------------------------------------------------------
// DeformableSpatialEncoder on MI355X (gfx950)
//
// R14 finding: gemm2 (128x128, swizzled) is latency/barrier-bound: 50us with
// MfmaUtil 12%, VALU 8%, HBM 16%, occ 26% -- FETCH fix (71->15MB) changed
// nothing. Instead of pipelining it, this round EXPLOITS LINEARITY of the
// deform step to delete 86% of its FLOPs and all of Vbuf:
//   core[n,ch] = sum_tok ws[n,m(ch),tok]*value[n,tok,ch] + sb*bias_v[ch]
//   value = A @ Wc_v^T + bc_v   (Wc_v = value_w @ We, folded as before)
//   => core[n,ch] = dot(Wc_v[ch,:], wa[n,m,:]) + sb[n,m]*bc_v[ch]
//      with wa[n,m,k] = sum_tok ws[n,m,tok]*A[n,tok,k]   (77 MF)
// Pipeline:
//   0. prep:    WeT bf16 = embed_w^T; Wcat_b bf16 concat; bcat2.
//   1. stage:   im2col A bf16 [12544,768] + fold-GEMM Wc[896,768]=Wcatb@WeT^T
//   2. gemm_oa: OA f32 [12544,64] = A @ Wc[768:816]^T + bcat2[768:816]
//               (LDS-free register MFMA; B rows L2-hot; 925 MF)
//   3. deform_wa: per (image, k-quarter): LDS ws[4][196] scatter (softmax x
//               bilinear, same math as old deform phase-1), then coalesced
//               A k-stream -> wa[64,4,768] f32 + sb[64,4]
//   4. core_wsum: core[n,ch] = (dot(Wc[ch,:], wa[n,m,:]) + sb*bcat2[ch])/196
//   5. pooled = core @ outp_w^T + outp_b;  final = pooled @ proj_w^T + proj_b
//      (small_linear_ks, R7-confirmed)
// ---------------------------------------------------------------------------

using bf16 = __bf16;
typedef bf16  bf16x4 __attribute__((ext_vector_type(4)));
typedef bf16  bf16x8 __attribute__((ext_vector_type(8)));
typedef float f32x4  __attribute__((ext_vector_type(4)));

#define N_IMG   64
#define LQ      196
#define DM      768
#define NH      4
#define DH      192
#define M_ROWS  (N_IMG * LQ)        // 12544
#define NCAT    896                 // 768 value + 32 off + 16 aw + 80 pad

// prep grid layout
#define P_WET    0                  // 288 blocks: WeT transpose-cast
#define P_WCAT   288                // 336 blocks: Wcat_b cast/concat
#define P_BCAT   624                // 4 blocks: bcat2
#define PREP_GRID 628

// stage grid layout
#define B_WGEMM   0                 // 42 blocks: 7 (o-tiles) x 6 (e-tiles)
#define B_IM2COL  42                // 9408 blocks
#define STAGE_GRID (B_IM2COL + 9408)

// ---- workspace layout (bytes, all 256-aligned) ----
#define OFF_A     ((size_t)0)                      // 12544*768*2 = 19267584
#define OFF_WC    (OFF_A     + 19267584)           // 896*768*2   = 1376256
#define OFF_BCAT  (OFF_WC    + 1376256)            // 4096
#define OFF_WA    (OFF_BCAT  + 4096)               // 64*4*768*4  = 786432
#define OFF_SB    (OFF_WA    + 786432)             // 4096
#define OFF_OA    (OFF_SB    + 4096)               // 12544*64*4  = 3211264
#define OFF_CORE  (OFF_OA    + 3211264)            // 196608
#define OFF_POOL  (OFF_CORE  + 196608)             // 196608
#define OFF_WCATB (OFF_POOL  + 196608)             // 896*768*2   = 1376256
#define OFF_WET   (OFF_WCATB + 1376256)            // 768*768*2   = 1179648

// ---------------------------------------------------------------------------
// prep: WeT transpose-cast, Wcat_b cast, bcat2. (core-zero pass removed:
// core is now fully written by core_wsum, wa fully written by deform_wa.)
// ---------------------------------------------------------------------------
__global__ void prep_kernel(const float* __restrict__ embed_w,
                            const float* __restrict__ embed_b,
                            const float* __restrict__ value_w,
                            const float* __restrict__ off_w,
                            const float* __restrict__ aw_w,
                            const float* __restrict__ value_b,
                            const float* __restrict__ off_b,
                            const float* __restrict__ aw_b,
                            bf16* __restrict__ WeT,
                            bf16* __restrict__ Wcatb,
                            float* __restrict__ bcat2) {
  const int bid = blockIdx.x;
  const int tid = threadIdx.x;

  if (bid < P_WCAT) {                    // ---- WeT[e][d] = embed_w[d][e] ----
    const int t = bid * 256 + tid;       // < 73728 exactly (288*256)
    const int e = t / 96;
    const int g = t - e * 96;            // d-group of 8
    bf16x8 o;
#pragma unroll
    for (int j = 0; j < 8; ++j)
      o[j] = (bf16)embed_w[(size_t)(g * 8 + j) * DM + e];
    *(bf16x8*)(WeT + (size_t)e * DM + g * 8) = o;
    return;
  }

  if (bid < P_BCAT) {                    // ---- Wcat_b cast/concat ----
    const int t = (bid - P_WCAT) * 256 + tid;   // < 86016 exactly (336*256)
    const int rr = t / 96;
    const int g  = t - rr * 96;
    const float* src = (rr < 768) ? value_w + (size_t)rr * DM
                     : (rr < 800) ? off_w + (size_t)(rr - 768) * DM
                     : (rr < 816) ? aw_w + (size_t)(rr - 800) * DM : nullptr;
    bf16x8 o;
    if (src) {
      const float4 f0 = *(const float4*)(src + g * 8);
      const float4 f1 = *(const float4*)(src + g * 8 + 4);
      o[0] = (bf16)f0.x; o[1] = (bf16)f0.y; o[2] = (bf16)f0.z; o[3] = (bf16)f0.w;
      o[4] = (bf16)f1.x; o[5] = (bf16)f1.y; o[6] = (bf16)f1.z; o[7] = (bf16)f1.w;
    } else {
#pragma unroll
      for (int j = 0; j < 8; ++j) o[j] = (bf16)0.f;
    }
    *(bf16x8*)(Wcatb + (size_t)rr * DM + g * 8) = o;
    return;
  }

  // ---- bcat2 = Wcat @ embed_b + bias ----
  const int o = (bid - P_BCAT) * 256 + tid;   // 0..1023
  if (o < NCAT) {
    float bias_o = (o < 768) ? value_b[o]
                 : (o < 800) ? off_b[o - 768]
                 : (o < 816) ? aw_b[o - 800] : 0.f;
    float acc = 0.f;
    if (o < 816) {
      const float* wr = (o < 768) ? value_w + (size_t)o * DM
                      : (o < 800) ? off_w + (size_t)(o - 768) * DM
                      : aw_w + (size_t)(o - 800) * DM;
      const float4* w4p = (const float4*)wr;
      const float4* b4p = (const float4*)embed_b;
#pragma unroll 4
      for (int k = 0; k < DM / 4; ++k) {
        const float4 wv = w4p[k], bv = b4p[k];
        acc += wv.x * bv.x + wv.y * bv.y + wv.z * bv.z + wv.w * bv.w;
      }
    }
    bcat2[o] = acc + bias_o;
  }
}

// ---------------------------------------------------------------------------
// stage: NO __shared__ (im2col occupancy stays wave-limited at 8 blocks/CU).
// blocks [0,42):    fold-GEMM Wc = Wcat_b @ WeT^T via register MFMA fragments
// blocks [42,9450): im2col, one thread = 4 consecutive k of one row.
// ---------------------------------------------------------------------------
__global__ void stage_kernel(const float* __restrict__ x,
                             const bf16* __restrict__ Wcatb,
                             const bf16* __restrict__ WeT,
                             bf16* __restrict__ A,
                             bf16* __restrict__ Wc) {
  const int bid = blockIdx.x;
  const int tid = threadIdx.x;

  if (bid >= B_IM2COL) {                 // ---- im2col ----
    const int t   = (bid - B_IM2COL) * 256 + tid;  // < 12544*192 exactly
    const int row = t / 192;
    const int j   = t - row * 192;
    const int k   = j * 4;               // k = c*256 + p*16 + q, q%4==0
    const int c   = k >> 8;
    const int r   = k & 255;
    const int p   = r >> 4;
    const int q   = r & 15;
    const int n   = row / 196;
    const int lq  = row - n * 196;
    const int h   = lq / 14;
    const int w   = lq - h * 14;
    const float4 v = *(const float4*)(x +
        ((((size_t)n * 3 + c) * 224) + h * 16 + p) * 224 + w * 16 + q);
    bf16x4 o;
    o[0] = (bf16)v.x; o[1] = (bf16)v.y; o[2] = (bf16)v.z; o[3] = (bf16)v.w;
    *(bf16x4*)(A + (size_t)row * DM + k) = o;
    return;
  }

  // ---- fold-GEMM: Wc[o,e] = sum_d Wcat_b[o,d] * WeT[e,d] ----
  const int mT = bid / 6;                // 0..6  o-tile
  const int nT = bid - mT * 6;           // 0..5  e-tile
  const int oBase = mT * 128;
  const int eBase = nT * 128;
  const int wave = tid >> 6;
  const int lane = tid & 63;
  const int quad = lane >> 4;
  const int r16  = lane & 15;
  const int wm = wave & 1;
  const int wn = wave >> 1;

  const f32x4 zero = {0.f, 0.f, 0.f, 0.f};
  f32x4 acc[4][4];
#pragma unroll
  for (int mi = 0; mi < 4; ++mi)
#pragma unroll
    for (int ni = 0; ni < 4; ++ni) acc[mi][ni] = zero;

  const bf16* Ab = Wcatb + (size_t)(oBase + wm * 64 + r16) * DM + quad * 8;
  const bf16* Bb = WeT   + (size_t)(eBase + wn * 64 + r16) * DM + quad * 8;

#pragma unroll 2
  for (int kk = 0; kk < DM; kk += 32) {
    bf16x8 af[4], bfr[4];
#pragma unroll
    for (int mi = 0; mi < 4; ++mi)
      af[mi] = *(const bf16x8*)(Ab + (size_t)mi * 16 * DM + kk);
#pragma unroll
    for (int ni = 0; ni < 4; ++ni)
      bfr[ni] = *(const bf16x8*)(Bb + (size_t)ni * 16 * DM + kk);
#pragma unroll
    for (int mi = 0; mi < 4; ++mi)
#pragma unroll
      for (int ni = 0; ni < 4; ++ni)
        acc[mi][ni] = __builtin_amdgcn_mfma_f32_16x16x32_bf16(
            af[mi], bfr[ni], acc[mi][ni], 0, 0, 0);
  }

#pragma unroll
  for (int ni = 0; ni < 4; ++ni) {
    const int col = eBase + wn * 64 + ni * 16 + r16;
#pragma unroll
    for (int mi = 0; mi < 4; ++mi) {
      const int row0 = oBase + wm * 64 + mi * 16 + quad * 4;
#pragma unroll
      for (int rr = 0; rr < 4; ++rr)
        Wc[(size_t)(row0 + rr) * DM + col] = (bf16)acc[mi][ni][rr];
    }
  }
}

// ---------------------------------------------------------------------------
// gemm_oa: OA[12544,64] = A @ Wc[768:816]^T + bcat2[768:816]  (925 MF)
// grid 196, block 256 (4 waves). Wave w owns rows [64b+16w, +16), cols 0..47.
// LDS-free: A fragments streamed from global (read once), B rows (48x768
// bf16 = 74KB) L2-hot and shared by all 196 blocks. No barriers at all.
// ---------------------------------------------------------------------------
__global__ void gemm_oa(const bf16* __restrict__ A, const bf16* __restrict__ Wc,
                        const float* __restrict__ bcat2, float* __restrict__ OA) {
  const int tid  = threadIdx.x;
  const int wave = tid >> 6;
  const int lane = tid & 63;
  const int quad = lane >> 4;
  const int r16  = lane & 15;
  const int rBase = blockIdx.x * 64 + wave * 16;

  const f32x4 zero = {0.f, 0.f, 0.f, 0.f};
  f32x4 acc[3];
#pragma unroll
  for (int ni = 0; ni < 3; ++ni) acc[ni] = zero;

  const bf16* Ab = A  + (size_t)(rBase + r16) * DM + quad * 8;
  const bf16* Bb = Wc + (size_t)(768 + r16) * DM + quad * 8;

#pragma unroll 4
  for (int kk = 0; kk < DM; kk += 32) {
    bf16x8 af = *(const bf16x8*)(Ab + kk);
    bf16x8 b0 = *(const bf16x8*)(Bb + kk);
    bf16x8 b1 = *(const bf16x8*)(Bb + (size_t)16 * DM + kk);
    bf16x8 b2 = *(const bf16x8*)(Bb + (size_t)32 * DM + kk);
    acc[0] = __builtin_amdgcn_mfma_f32_16x16x32_bf16(af, b0, acc[0], 0, 0, 0);
    acc[1] = __builtin_amdgcn_mfma_f32_16x16x32_bf16(af, b1, acc[1], 0, 0, 0);
    acc[2] = __builtin_amdgcn_mfma_f32_16x16x32_bf16(af, b2, acc[2], 0, 0, 0);
  }

  // C layout: row = quad*4+rr (within 16-row frag), col = r16
#pragma unroll
  for (int ni = 0; ni < 3; ++ni) {
    const int o = ni * 16 + r16;        // 0..47
    const float bv = bcat2[768 + o];
#pragma unroll
    for (int rr = 0; rr < 4; ++rr) {
      const int row = rBase + quad * 4 + rr;
      OA[(size_t)row * 64 + o] = acc[ni][rr] + bv;
    }
  }
}

// ---------------------------------------------------------------------------
// deform_wa: grid (64, 4), block 192.  y = k-quarter (192 k's).
// Phase 1: ws[4][196] in LDS via atomicAdd -- per (lq,m,p) item, same
//   softmax x bilinear x validity math as the old deform phase-1, scattered
//   into per-head token bins.
// Phase 2: thread = one k; stream 196 A rows (coalesced 2B lane-consecutive)
//   accumulating 4 head sums; write wa[n][m][k] (each (n,k) owned once --
//   no global atomics, no zero-init). Block y==0 also writes sb[n][m].
// ---------------------------------------------------------------------------
__global__ void deform_wa(const bf16* __restrict__ A,
                          const float* __restrict__ OA,
                          float* __restrict__ wa,
                          float* __restrict__ sb) {
  __shared__ float s_ws[4][196];
  const int n   = blockIdx.x;
  const int yq  = blockIdx.y;
  const int tid = threadIdx.x;

  for (int i = tid; i < 4 * 196; i += 192) ((float*)s_ws)[i] = 0.f;
  __syncthreads();

  for (int it = tid; it < 3136; it += 192) {   // 196 lq x 4 m x 4 p
    const int lq = it >> 4;
    const int m  = (it >> 2) & 3;
    const int p  = it & 3;
    const float* row = OA + ((size_t)n * LQ + lq) * 64;

    const float l0 = row[32 + m * 4 + 0];
    const float l1 = row[32 + m * 4 + 1];
    const float l2 = row[32 + m * 4 + 2];
    const float l3 = row[32 + m * 4 + 3];
    const float mx = fmaxf(fmaxf(l0, l1), fmaxf(l2, l3));
    const float e0 = __expf(l0 - mx), e1 = __expf(l1 - mx);
    const float e2 = __expf(l2 - mx), e3 = __expf(l3 - mx);
    const float inv = 1.f / (e0 + e1 + e2 + e3);
    const float ep[4] = {e0, e1, e2, e3};
    const float ew = ep[p] * inv;

    const int h = lq / 14, w = lq - (lq / 14) * 14;
    // px = w*14/13 + offx - 0.5  (ref linspace(0,1,14), normalizer W=14)
    const float px = (float)w * (14.f / 13.f) - 0.5f + row[(m * 4 + p) * 2 + 0];
    const float py = (float)h * (14.f / 13.f) - 0.5f + row[(m * 4 + p) * 2 + 1];
    const float fx = floorf(px), fy = floorf(py);
    const int x0 = (int)fx, y0 = (int)fy;
    const float wx1 = px - fx, wy1 = py - fy;
    const float wx0 = 1.f - wx1, wy0 = 1.f - wy1;

    const bool vx0 = (x0 >= 0) & (x0 < 14);
    const bool vx1 = (x0 >= -1) & (x0 < 13);
    const bool vy0 = (y0 >= 0) & (y0 < 14);
    const bool vy1 = (y0 >= -1) & (y0 < 13);
    const int cx0 = min(max(x0, 0), 13),      cx1 = min(max(x0 + 1, 0), 13);
    const int cy0 = min(max(y0, 0), 13) * 14, cy1 = min(max(y0 + 1, 0), 13) * 14;

    const float w0 = (vx0 & vy0) ? ew * wx0 * wy0 : 0.f;
    const float w1 = (vx1 & vy0) ? ew * wx1 * wy0 : 0.f;
    const float w2 = (vx0 & vy1) ? ew * wx0 * wy1 : 0.f;
    const float w3 = (vx1 & vy1) ? ew * wx1 * wy1 : 0.f;
    atomicAdd(&s_ws[m][cy0 + cx0], w0);
    atomicAdd(&s_ws[m][cy0 + cx1], w1);
    atomicAdd(&s_ws[m][cy1 + cx0], w2);
    atomicAdd(&s_ws[m][cy1 + cx1], w3);
  }
  __syncthreads();

  const int k = yq * 192 + tid;
  const bf16* ap = A + (size_t)n * LQ * DM + k;
  float wam0 = 0.f, wam1 = 0.f, wam2 = 0.f, wam3 = 0.f;
#pragma unroll 4
  for (int tok = 0; tok < 196; ++tok) {
    const float a = (float)ap[(size_t)tok * DM];
    wam0 += s_ws[0][tok] * a;
    wam1 += s_ws[1][tok] * a;
    wam2 += s_ws[2][tok] * a;
    wam3 += s_ws[3][tok] * a;
  }
  float* wp = wa + (size_t)n * 4 * DM + k;
  wp[0 * DM] = wam0;
  wp[1 * DM] = wam1;
  wp[2 * DM] = wam2;
  wp[3 * DM] = wam3;

  if (yq == 0 && tid < 4) {
    float s = 0.f;
    for (int tok = 0; tok < 196; ++tok) s += s_ws[tid][tok];
    sb[n * 4 + tid] = s;
  }
}

// ---------------------------------------------------------------------------
// core_wsum: core[n,ch] = (dot(Wc[ch,:], wa[n,m(ch),:]) + sb[n,m]*bcat2[ch])/196
// grid (16, 12), block 256 = 4 waves. Each block: 4 images x 64-channel chunk
// (chunk lies within one head: 192 = 3*64). wa rows staged in LDS (12KB,
// broadcast reads); Wc row read bf16x8 coalesced; K split across 4 waves.
// ---------------------------------------------------------------------------
__global__ void core_wsum(const float* __restrict__ wa,
                          const float* __restrict__ sb,
                          const bf16* __restrict__ Wc,
                          const float* __restrict__ bcat2,
                          float* __restrict__ core) {
  __shared__ float s_wa[4 * DM];           // 12 KB: [img][k]
  __shared__ float s_red[3][4][64];        // 3 KB
  __shared__ float s_sbv[4];
  const int tid = threadIdx.x;
  const int n0  = blockIdx.x * 4;
  const int m   = blockIdx.y / 3;          // head (64-chunk within one head)

#pragma unroll
  for (int i = 0; i < 3; ++i) {            // 768 float4 total
    const int t   = tid + i * 256;
    const int img = t / 192;
    const int k4  = t - img * 192;
    ((float4*)s_wa)[(size_t)img * 192 + k4] =
        ((const float4*)(wa + ((size_t)(n0 + img) * 4 + m) * DM))[k4];
  }
  if (tid < 4) s_sbv[tid] = sb[(n0 + tid) * 4 + m];
  __syncthreads();

  const int dl = tid & 63;
  const int ks = tid >> 6;                 // wave id = K-quarter
  const int d  = blockIdx.y * 64 + dl;     // channel
  const int k0 = ks * 192;

  const bf16* wrow = Wc + (size_t)d * DM + k0;
  const float* p0 = s_wa + 0 * DM + k0;
  const float* p1 = s_wa + 1 * DM + k0;
  const float* p2 = s_wa + 2 * DM + k0;
  const float* p3 = s_wa + 3 * DM + k0;
  float a0 = 0.f, a1 = 0.f, a2 = 0.f, a3 = 0.f;
#pragma unroll 4
  for (int k = 0; k < 192; k += 8) {
    const bf16x8 wv = *(const bf16x8*)(wrow + k);
#pragma unroll
    for (int j = 0; j < 8; ++j) {
      const float w = (float)wv[j];
      a0 += w * p0[k + j];
      a1 += w * p1[k + j];
      a2 += w * p2[k + j];
      a3 += w * p3[k + j];
    }
  }

  if (ks > 0) {
    s_red[ks - 1][0][dl] = a0;
    s_red[ks - 1][1][dl] = a1;
    s_red[ks - 1][2][dl] = a2;
    s_red[ks - 1][3][dl] = a3;
  }
  __syncthreads();
  if (ks == 0) {
#pragma unroll
    for (int w = 0; w < 3; ++w) {
      a0 += s_red[w][0][dl];
      a1 += s_red[w][1][dl];
      a2 += s_red[w][2][dl];
      a3 += s_red[w][3][dl];
    }
    const float bv = bcat2[d];
    core[(size_t)(n0 + 0) * DM + d] = (a0 + s_sbv[0] * bv) * (1.f / 196.f);
    core[(size_t)(n0 + 1) * DM + d] = (a1 + s_sbv[1] * bv) * (1.f / 196.f);
    core[(size_t)(n0 + 2) * DM + d] = (a2 + s_sbv[2] * bv) * (1.f / 196.f);
    core[(size_t)(n0 + 3) * DM + d] = (a3 + s_sbv[3] * bv) * (1.f / 196.f);
  }
}

// ---------------------------------------------------------------------------
// small_linear_ks: out[n][d] = sum_k in[n][k] * W[d][k] + b[d]
// grid (N_IMG/4, DM/64), block 256 = 4 waves. 4 images/block share W reads;
// K split across the 4 waves, LDS cross-wave reduce. (R7: confirmed fix.)
// ---------------------------------------------------------------------------
__global__ void small_linear_ks(const float* __restrict__ in,
                                const float* __restrict__ W,
                                const float* __restrict__ b,
                                float* __restrict__ out) {
  __shared__ float s_in[4 * DM];           // 12 KB
  __shared__ float s_red[3][4][64];        // 3 KB
  const int tid = threadIdx.x;
  const int n0 = blockIdx.x * 4;
  const float4* src = (const float4*)(in + (size_t)n0 * DM);
#pragma unroll
  for (int i = 0; i < 3; ++i)              // 4*768 floats = 768 float4
    ((float4*)s_in)[tid + i * 256] = src[tid + i * 256];
  __syncthreads();

  const int dl = tid & 63;
  const int ks = tid >> 6;                 // wave id = K-quarter
  const int d  = blockIdx.y * 64 + dl;
  const int k0 = ks * (DM / 4);            // 192 floats per wave

  const float4* w4p = (const float4*)(W + (size_t)d * DM + k0);
  const float4* s0 = (const float4*)(s_in + k0);
  const float4* s1 = (const float4*)(s_in + DM + k0);
  const float4* s2 = (const float4*)(s_in + 2 * DM + k0);
  const float4* s3 = (const float4*)(s_in + 3 * DM + k0);
  float a0 = 0.f, a1 = 0.f, a2 = 0.f, a3 = 0.f;
#pragma unroll 8
  for (int k = 0; k < DM / 16; ++k) {      // 48 float4 iterations
    const float4 w = w4p[k];
    const float4 v0 = s0[k], v1 = s1[k], v2 = s2[k], v3 = s3[k];
    a0 += w.x * v0.x + w.y * v0.y + w.z * v0.z + w.w * v0.w;
    a1 += w.x * v1.x + w.y * v1.y + w.z * v1.z + w.w * v1.w;
    a2 += w.x * v2.x + w.y * v2.y + w.z * v2.z + w.w * v2.w;
    a3 += w.x * v3.x + w.y * v3.y + w.z * v3.z + w.w * v3.w;
  }

  if (ks > 0) {
    s_red[ks - 1][0][dl] = a0;
    s_red[ks - 1][1][dl] = a1;
    s_red[ks - 1][2][dl] = a2;
    s_red[ks - 1][3][dl] = a3;
  }
  __syncthreads();
  if (ks == 0) {
#pragma unroll
    for (int w = 0; w < 3; ++w) {
      a0 += s_red[w][0][dl];
      a1 += s_red[w][1][dl];
      a2 += s_red[w][2][dl];
      a3 += s_red[w][3][dl];
    }
    const float bv = b[d];
    out[(size_t)(n0 + 0) * DM + d] = a0 + bv;
    out[(size_t)(n0 + 1) * DM + d] = a1 + bv;
    out[(size_t)(n0 + 2) * DM + d] = a2 + bv;
    out[(size_t)(n0 + 3) * DM + d] = a3 + bv;
  }
}

// ---------------------------------------------------------------------------
extern "C" void kernel_launch(void* const* d_in, const int* in_sizes, int n_in,
                              void* d_out, int out_size, void* d_ws, size_t ws_size,
                              hipStream_t stream) {
  const float* x       = (const float*)d_in[0];
  const float* embed_w = (const float*)d_in[1];
  const float* embed_b = (const float*)d_in[2];
  const float* value_w = (const float*)d_in[3];
  const float* value_b = (const float*)d_in[4];
  const float* off_w   = (const float*)d_in[5];
  const float* off_b   = (const float*)d_in[6];
  const float* aw_w    = (const float*)d_in[7];
  const float* aw_b    = (const float*)d_in[8];
  const float* outp_w  = (const float*)d_in[9];
  const float* outp_b  = (const float*)d_in[10];
  const float* proj_w  = (const float*)d_in[11];
  const float* proj_b  = (const float*)d_in[12];
  float* out = (float*)d_out;

  char* ws = (char*)d_ws;
  bf16*  A      = (bf16*)(ws + OFF_A);
  bf16*  Wc     = (bf16*)(ws + OFF_WC);
  float* bcat2  = (float*)(ws + OFF_BCAT);
  float* wa     = (float*)(ws + OFF_WA);
  float* sb     = (float*)(ws + OFF_SB);
  float* OA     = (float*)(ws + OFF_OA);
  float* core   = (float*)(ws + OFF_CORE);
  float* pooled = (float*)(ws + OFF_POOL);
  bf16*  Wcatb  = (bf16*)(ws + OFF_WCATB);
  bf16*  WeT    = (bf16*)(ws + OFF_WET);

  prep_kernel<<<dim3(PREP_GRID), dim3(256), 0, stream>>>(
      embed_w, embed_b, value_w, off_w, aw_w, value_b, off_b, aw_b,
      WeT, Wcatb, bcat2);

  stage_kernel<<<dim3(STAGE_GRID), dim3(256), 0, stream>>>(
      x, Wcatb, WeT, A, Wc);

  gemm_oa<<<dim3(M_ROWS / 64), dim3(256), 0, stream>>>(A, Wc, bcat2, OA);

  deform_wa<<<dim3(N_IMG, 4), dim3(192), 0, stream>>>(A, OA, wa, sb);

  core_wsum<<<dim3(N_IMG / 4, DM / 64), dim3(256), 0, stream>>>(
      wa, sb, Wc, bcat2, core);

  small_linear_ks<<<dim3(N_IMG / 4, DM / 64), dim3(256), 0, stream>>>(
      core, outp_w, outp_b, pooled);
  small_linear_ks<<<dim3(N_IMG / 4, DM / 64), dim3(256), 0, stream>>>(
      pooled, proj_w, proj_b, out);
}